// Round 1
// baseline (65025.549 us; speedup 1.0000x reference)
//
#include <hip/hip_runtime.h>
#include <hip/hip_bf16.h>

#define TT 512
#define BB 64
#define HH 128
#define WW 128
#define DD 32
#define HD 4096
#define NTHR 512
#define WSTR 132   // padded LDS stride for 128-col fp32 weight rows (16B aligned, spread banks)

// LDS layout (floats): w0[128*132] w1[128*132] rowbuf[4096] y[128] ytmp[128] k1[128] k2[128] k3[128] h1[128] h2[128] dvec[96]
#define SMEM_FLOATS (128*WSTR*2 + HD + HH*5 + WW*2 + 96)

__device__ __forceinline__ float blo(unsigned u) { return __uint_as_float(u << 16); }
__device__ __forceinline__ float bhi(unsigned u) { return __uint_as_float(u & 0xffff0000u); }

__device__ __forceinline__ float softplus_f(float x) {
    return fmaxf(x, 0.f) + log1pf(__expf(-fabsf(x)));
}
__device__ __forceinline__ float fast_tanh(float x) {
    float ax = fabsf(x);
    float e  = __expf(-2.f * ax);          // in (0,1], no overflow
    float r  = (1.f - e) / (1.f + e);      // tanh(ax)
    return copysignf(r, x);
}

__global__ void cvt_w2_bf16(const float* __restrict__ w2, __hip_bfloat16* __restrict__ o, int n) {
    int i = blockIdx.x * blockDim.x + threadIdx.x;
    if (i < n) o[i] = __float2bfloat16(w2[i]);
}

template <bool USEB16>
__global__ __launch_bounds__(NTHR)
void cde_kernel(const float* __restrict__ ts,
                const float* __restrict__ cd, const float* __restrict__ cc,
                const float* __restrict__ cb, const float* __restrict__ ca,
                const float* __restrict__ iW0, const float* __restrict__ ib0,
                const float* __restrict__ iW1, const float* __restrict__ ib1,
                const float* __restrict__ iW2, const float* __restrict__ ib2,
                const float* __restrict__ fW0, const float* __restrict__ fb0,
                const float* __restrict__ fW1, const float* __restrict__ fb1,
                const float* __restrict__ fW2, const float* __restrict__ fb2,
                const float* __restrict__ lW, const float* __restrict__ lb,
                const __hip_bfloat16* __restrict__ w2b,
                float* __restrict__ out)
{
    extern __shared__ float sm[];
    float* w0     = sm;
    float* w1     = w0 + 128 * WSTR;
    float* rowbuf = w1 + 128 * WSTR;
    float* ybuf   = rowbuf + HD;
    float* ytmp   = ybuf + HH;
    float* k1b    = ytmp + HH;
    float* k2b    = k1b + HH;
    float* k3b    = k2b + HH;   // (kept for symmetry; stage-3 k folded directly)
    float* h1b    = k3b + HH;
    float* h2b    = h1b + WW;
    float* dvec   = h2b + WW;   // 3*32

    const int tid  = threadIdx.x;
    const int b    = blockIdx.x;
    const int lane = tid & 63;
    const int wv   = tid >> 6;
    const int sub  = lane >> 4;   // 0..3 : row within wave's 4-row pass
    const int lk   = lane & 15;   // 0..15: 8-col group within row

    const float* tsb = ts + (size_t)b * TT;
    const float  t_start = tsb[0];
    const float  dt = tsb[1] - t_start;

    // ---- stage weights into LDS (padded) ----
    for (int i = tid; i < WW * HH; i += NTHR) {
        int r = i >> 7, c = i & 127;
        w0[r * WSTR + c] = fW0[i];
        w1[r * WSTR + c] = fW1[i];
    }

    // ---- initial_mlp on a[b][0][:] (relu,relu,identity), fp32 ----
    const size_t cstride = (size_t)(TT - 1) * DD;
    if (tid < WW) {
        float acc = ib0[tid];
        const float* a0 = ca + (size_t)b * cstride;
        #pragma unroll
        for (int k = 0; k < DD; ++k) acc += iW0[tid * DD + k] * a0[k];
        h1b[tid] = fmaxf(acc, 0.f);
    }
    __syncthreads();
    if (tid < WW) {
        float acc = ib1[tid];
        for (int k = 0; k < WW; ++k) acc += iW1[tid * WW + k] * h1b[k];
        h2b[tid] = fmaxf(acc, 0.f);
    }
    __syncthreads();
    if (tid < HH) {
        float acc = ib2[tid];
        for (int k = 0; k < WW; ++k) acc += iW2[tid * WW + k] * h2b[k];
        ybuf[tid] = acc;
    }
    __syncthreads();

    // readout weights held in wave-0 registers
    float lw0 = 0.f, lw1 = 0.f, lbv = 0.f;
    if (wv == 0) { lw0 = lW[lane]; lw1 = lW[lane + 64]; lbv = lb[0]; }

    const float* cdb = cd + (size_t)b * cstride;
    const float* ccb = cc + (size_t)b * cstride;
    const float* cbb = cb + (size_t)b * cstride;

    float t0 = t_start;

    for (int s = 0; s < TT; ++s) {
        const float tv0 = t0;
        const float tv1 = t0 + 0.5f  * dt;
        const float tv2 = t0 + 0.75f * dt;

        // searchsorted(ts, t, 'right') - 1, clipped — O(1) via block-wide count
        const float myts = tsb[tid];
        int i0 = __syncthreads_count(myts <= tv0);
        int i1 = __syncthreads_count(myts <= tv1);
        int i2 = __syncthreads_count(myts <= tv2);
        i0 = min(max(i0 - 1, 0), TT - 2);
        i1 = min(max(i1 - 1, 0), TT - 2);
        i2 = min(max(i2 - 1, 0), TT - 2);

        if (tid < 96) {
            int q = tid >> 5, d = tid & 31;
            int idx = (q == 0) ? i0 : (q == 1) ? i1 : i2;
            float tv = (q == 0) ? tv0 : (q == 1) ? tv1 : tv2;
            float frac = tv - tsb[idx];
            size_t o = (size_t)idx * DD + d;
            dvec[q * DD + d] = cbb[o] + frac * (2.f * ccb[o] + frac * 3.f * cdb[o]);
        }
        __syncthreads();

        const float* yin = ybuf;
        #pragma unroll 1
        for (int q = 0; q < 3; ++q) {
            // ---- hidden layer 1: h1 = softplus(fW0 @ yin + fb0), 4 lanes/row ----
            {
                const int row = tid >> 2, kq = (tid & 3) * 32;
                const float* wr = w0 + row * WSTR + kq;
                const float* xr = yin + kq;
                float acc = 0.f;
                #pragma unroll
                for (int k = 0; k < 32; k += 4) {
                    float4 wv4 = *(const float4*)(wr + k);
                    float4 xv4 = *(const float4*)(xr + k);
                    acc += wv4.x * xv4.x + wv4.y * xv4.y + wv4.z * xv4.z + wv4.w * xv4.w;
                }
                acc += __shfl_xor(acc, 1);
                acc += __shfl_xor(acc, 2);
                if ((tid & 3) == 0) h1b[row] = softplus_f(acc + fb0[row]);
            }
            __syncthreads();
            // ---- hidden layer 2 ----
            {
                const int row = tid >> 2, kq = (tid & 3) * 32;
                const float* wr = w1 + row * WSTR + kq;
                const float* xr = h1b + kq;
                float acc = 0.f;
                #pragma unroll
                for (int k = 0; k < 32; k += 4) {
                    float4 wv4 = *(const float4*)(wr + k);
                    float4 xv4 = *(const float4*)(xr + k);
                    acc += wv4.x * xv4.x + wv4.y * xv4.y + wv4.z * xv4.z + wv4.w * xv4.w;
                }
                acc += __shfl_xor(acc, 1);
                acc += __shfl_xor(acc, 2);
                if ((tid & 3) == 0) h2b[row] = softplus_f(acc + fb1[row]);
            }
            __syncthreads();

            // ---- big matvec: rowsum[r] = fW2[r,:] . h2  (coalesced, 16 lanes/row) ----
            float h2r[8];
            #pragma unroll
            for (int j = 0; j < 8; ++j) h2r[j] = h2b[lk * 8 + j];

            #pragma unroll 2
            for (int p = 0; p < 128; ++p) {
                const int r = p * 32 + wv * 4 + sub;
                float acc2;
                if (USEB16) {
                    uint4 u = *(const uint4*)(w2b + (size_t)r * WW + lk * 8);
                    acc2 = blo(u.x) * h2r[0] + bhi(u.x) * h2r[1]
                         + blo(u.y) * h2r[2] + bhi(u.y) * h2r[3]
                         + blo(u.z) * h2r[4] + bhi(u.z) * h2r[5]
                         + blo(u.w) * h2r[6] + bhi(u.w) * h2r[7];
                } else {
                    const float* wr2 = fW2 + (size_t)r * WW + lk * 8;
                    float4 a0 = *(const float4*)(wr2);
                    float4 a1 = *(const float4*)(wr2 + 4);
                    acc2 = a0.x * h2r[0] + a0.y * h2r[1] + a0.z * h2r[2] + a0.w * h2r[3]
                         + a1.x * h2r[4] + a1.y * h2r[5] + a1.z * h2r[6] + a1.w * h2r[7];
                }
                acc2 += __shfl_xor(acc2, 1);
                acc2 += __shfl_xor(acc2, 2);
                acc2 += __shfl_xor(acc2, 4);
                acc2 += __shfl_xor(acc2, 8);
                if (lk == 0) rowbuf[r] = acc2;
            }
            __syncthreads();

            // ---- bias + tanh, batched ----
            {
                const int base = tid * 8;
                float4 r0 = *(const float4*)(rowbuf + base);
                float4 r1 = *(const float4*)(rowbuf + base + 4);
                float4 b0 = *(const float4*)(fb2 + base);
                float4 b1 = *(const float4*)(fb2 + base + 4);
                r0.x = fast_tanh(r0.x + b0.x); r0.y = fast_tanh(r0.y + b0.y);
                r0.z = fast_tanh(r0.z + b0.z); r0.w = fast_tanh(r0.w + b0.w);
                r1.x = fast_tanh(r1.x + b1.x); r1.y = fast_tanh(r1.y + b1.y);
                r1.z = fast_tanh(r1.z + b1.z); r1.w = fast_tanh(r1.w + b1.w);
                *(float4*)(rowbuf + base)     = r0;
                *(float4*)(rowbuf + base + 4) = r1;
            }
            __syncthreads();

            // ---- contract over D with dvec, form k, advance stage input ----
            {
                const int h = tid >> 2, dg = tid & 3;
                const float* dv = dvec + q * DD + dg * 8;
                const float* rb = rowbuf + h * DD + dg * 8;
                float p2 = 0.f;
                #pragma unroll
                for (int j = 0; j < 8; ++j) p2 += rb[j] * dv[j];
                p2 += __shfl_xor(p2, 1);
                p2 += __shfl_xor(p2, 2);
                if (dg == 0) {
                    float kv = p2 * dt;   // f = (M @ deriv) * dt
                    if (q == 0)      { k1b[h] = kv; ytmp[h] = ybuf[h] + 0.5f  * kv; }
                    else if (q == 1) { k2b[h] = kv; ytmp[h] = ybuf[h] + 0.75f * kv; }
                    else {
                        ybuf[h] = ybuf[h] + dt * ((2.f/9.f) * k1b[h] + (1.f/3.f) * k2b[h] + (4.f/9.f) * kv);
                    }
                }
            }
            __syncthreads();
            yin = ytmp;
        }

        // ---- readout: sigmoid(y . lW + lb) ----
        if (wv == 0) {
            float p = ybuf[lane] * lw0 + ybuf[lane + 64] * lw1;
            p += __shfl_xor(p, 1);
            p += __shfl_xor(p, 2);
            p += __shfl_xor(p, 4);
            p += __shfl_xor(p, 8);
            p += __shfl_xor(p, 16);
            p += __shfl_xor(p, 32);
            if (lane == 0) out[(size_t)b * TT + s] = 1.f / (1.f + __expf(-(p + lbv)));
        }
        t0 += dt;
        __syncthreads();
    }
}

extern "C" void kernel_launch(void* const* d_in, const int* in_sizes, int n_in,
                              void* d_out, int out_size, void* d_ws, size_t ws_size,
                              hipStream_t stream) {
    const float* ts  = (const float*)d_in[0];
    const float* cdp = (const float*)d_in[1];
    const float* ccp = (const float*)d_in[2];
    const float* cbp = (const float*)d_in[3];
    const float* cap = (const float*)d_in[4];
    const float* iW0 = (const float*)d_in[5];
    const float* ib0 = (const float*)d_in[6];
    const float* iW1 = (const float*)d_in[7];
    const float* ib1 = (const float*)d_in[8];
    const float* iW2 = (const float*)d_in[9];
    const float* ib2 = (const float*)d_in[10];
    const float* fW0 = (const float*)d_in[11];
    const float* fb0 = (const float*)d_in[12];
    const float* fW1 = (const float*)d_in[13];
    const float* fb1 = (const float*)d_in[14];
    const float* fW2 = (const float*)d_in[15];
    const float* fb2 = (const float*)d_in[16];
    const float* lW  = (const float*)d_in[17];
    const float* lb  = (const float*)d_in[18];
    float* out = (float*)d_out;

    const int n_w2 = HD * WW;  // 524288
    const bool useb16 = ws_size >= (size_t)n_w2 * sizeof(__hip_bfloat16);
    __hip_bfloat16* w2b = (__hip_bfloat16*)d_ws;

    const size_t smem_bytes = SMEM_FLOATS * sizeof(float);

    if (useb16) {
        hipLaunchKernelGGL(cvt_w2_bf16, dim3((n_w2 + 255) / 256), dim3(256), 0, stream, fW2, w2b, n_w2);
        static bool attr_set = [&]() {
            hipFuncSetAttribute((const void*)cde_kernel<true>,
                                hipFuncAttributeMaxDynamicSharedMemorySize, (int)smem_bytes);
            return true;
        }();
        (void)attr_set;
        hipFuncSetAttribute((const void*)cde_kernel<true>,
                            hipFuncAttributeMaxDynamicSharedMemorySize, (int)smem_bytes);
        hipLaunchKernelGGL((cde_kernel<true>), dim3(BB), dim3(NTHR), smem_bytes, stream,
                           ts, cdp, ccp, cbp, cap, iW0, ib0, iW1, ib1, iW2, ib2,
                           fW0, fb0, fW1, fb1, fW2, fb2, lW, lb, w2b, out);
    } else {
        hipFuncSetAttribute((const void*)cde_kernel<false>,
                            hipFuncAttributeMaxDynamicSharedMemorySize, (int)smem_bytes);
        hipLaunchKernelGGL((cde_kernel<false>), dim3(BB), dim3(NTHR), smem_bytes, stream,
                           ts, cdp, ccp, cbp, cap, iW0, ib0, iW1, ib1, iW2, ib2,
                           fW0, fb0, fW1, fb1, fW2, fb2, lW, lb, (const __hip_bfloat16*)nullptr, out);
    }
}

// Round 2
// 17147.981 us; speedup vs baseline: 3.7920x; 3.7920x over previous
//
#include <hip/hip_runtime.h>
#include <hip/hip_bf16.h>

#define TT 512
#define BB 64
#define HH 128
#define WW 128
#define DD 32
#define HD 4096
#define NTHR 1024
#define WSTR 132   // padded LDS stride for 128-col fp32 weight rows

// LDS (floats): w0[128*132] w1[128*132] rowbuf[4096] tss[512] y[128] ytmp[128]
//               k1[128] k2[128] h1[128] h2[128] dvec[96]
#define SMEM_FLOATS (128*WSTR*2 + HD + TT + HH*4 + WW*2 + 96)

typedef __attribute__((ext_vector_type(8))) short short8;
typedef __attribute__((ext_vector_type(4))) float f32x4;

__device__ __forceinline__ float softplus_f(float x) {
    return fmaxf(x, 0.f) + log1pf(__expf(-fabsf(x)));
}
__device__ __forceinline__ float fast_tanh(float x) {
    float ax = fabsf(x);
    float e  = __expf(-2.f * ax);
    float r  = (1.f - e) / (1.f + e);
    return copysignf(r, x);
}
__device__ __forceinline__ short bf16rne(float x) {
    unsigned u = __float_as_uint(x);
    u += 0x7fffu + ((u >> 16) & 1u);
    return (short)(u >> 16);
}

// Permute fW2 (4096x128 row-major fp32) into bf16 MFMA-A-fragment-linear tiles.
// Tile block index: block = h*8 + t*4 + K  (h=0..127 row-group of 32, t=0..1 sub-tile
// of 16 rows, K=0..3 k-block of 32). Within block: 512 bf16, lane l (0..63) owns
// elements l*8+j = A[row = (l&15)][k = (l>>4)*8 + j] of that 16x32 tile.
__global__ void cvt_w2_perm(const float* __restrict__ w2, short* __restrict__ o, int n) {
    int e = blockIdx.x * blockDim.x + threadIdx.x;
    if (e >= n) return;
    int j = e & 7;
    int l = (e >> 3) & 63;
    int block = e >> 9;
    int K = block & 3;
    int t = (block >> 2) & 1;
    int h = block >> 3;
    int r = h * 32 + t * 16 + (l & 15);
    int c = K * 32 + (l >> 4) * 8 + j;
    o[e] = bf16rne(w2[r * WW + c]);
}

__global__ __launch_bounds__(NTHR)
void cde_kernel(const float* __restrict__ ts,
                const float* __restrict__ cd, const float* __restrict__ cc,
                const float* __restrict__ cb, const float* __restrict__ ca,
                const float* __restrict__ iW0, const float* __restrict__ ib0,
                const float* __restrict__ iW1, const float* __restrict__ ib1,
                const float* __restrict__ iW2, const float* __restrict__ ib2,
                const float* __restrict__ fW0, const float* __restrict__ fb0,
                const float* __restrict__ fW1, const float* __restrict__ fb1,
                const float* __restrict__ fb2,
                const float* __restrict__ lW, const float* __restrict__ lb,
                const short* __restrict__ w2p,
                float* __restrict__ out)
{
    extern __shared__ float sm[];
    float* w0     = sm;
    float* w1     = w0 + 128 * WSTR;
    float* rowbuf = w1 + 128 * WSTR;
    float* tss    = rowbuf + HD;
    float* ybuf   = tss + TT;
    float* ytmp   = ybuf + HH;
    float* k1b    = ytmp + HH;
    float* k2b    = k1b + HH;
    float* h1b    = k2b + HH;
    float* h2b    = h1b + WW;
    float* dvec   = h2b + WW;   // 3*32

    const int tid  = threadIdx.x;
    const int b    = blockIdx.x;
    const int lane = tid & 63;
    const int wv   = tid >> 6;

    // ---- stage weights + ts into LDS ----
    for (int i = tid; i < WW * HH; i += NTHR) {
        int r = i >> 7, c = i & 127;
        w0[r * WSTR + c] = fW0[i];
        w1[r * WSTR + c] = fW1[i];
    }
    if (tid < TT) tss[tid] = ts[(size_t)b * TT + tid];
    __syncthreads();

    const float dt = tss[1] - tss[0];
    const size_t cstride = (size_t)(TT - 1) * DD;
    const float* cdb = cd + (size_t)b * cstride;
    const float* ccb = cc + (size_t)b * cstride;
    const float* cbb = cb + (size_t)b * cstride;

    const int row8 = tid >> 3;        // 0..127
    const int oct  = tid & 7;         // 0..7

    // ---- initial_mlp on ca[b][0][:] (relu, relu, identity), fp32, 8 lanes/row ----
    {
        const float* a0 = ca + (size_t)b * cstride;
        float acc = 0.f;
        #pragma unroll
        for (int j = 0; j < 4; ++j) acc += iW0[row8 * DD + oct * 4 + j] * a0[oct * 4 + j];
        acc += __shfl_xor(acc, 1); acc += __shfl_xor(acc, 2); acc += __shfl_xor(acc, 4);
        if (oct == 0) h1b[row8] = fmaxf(acc + ib0[row8], 0.f);
    }
    __syncthreads();
    {
        float acc = 0.f;
        #pragma unroll
        for (int k = 0; k < 16; ++k) acc += iW1[row8 * WW + oct * 16 + k] * h1b[oct * 16 + k];
        acc += __shfl_xor(acc, 1); acc += __shfl_xor(acc, 2); acc += __shfl_xor(acc, 4);
        if (oct == 0) h2b[row8] = fmaxf(acc + ib1[row8], 0.f);
    }
    __syncthreads();
    {
        float acc = 0.f;
        #pragma unroll
        for (int k = 0; k < 16; ++k) acc += iW2[row8 * WW + oct * 16 + k] * h2b[oct * 16 + k];
        acc += __shfl_xor(acc, 1); acc += __shfl_xor(acc, 2); acc += __shfl_xor(acc, 4);
        if (oct == 0) ybuf[row8] = acc + ib2[row8];
    }
    __syncthreads();

    // readout weights in wave-0 registers
    float lw0 = 0.f, lw1 = 0.f, lbv = 0.f;
    if (wv == 0) { lw0 = lW[lane]; lw1 = lW[lane + 64]; lbv = lb[0]; }

    const float myts = (tid < TT) ? tss[tid] : 3.4e38f;
    float t0 = tss[0];

    for (int s = 0; s < TT; ++s) {
        const float tv0 = t0;
        const float tv1 = t0 + 0.5f  * dt;
        const float tv2 = t0 + 0.75f * dt;

        // searchsorted(ts, t, 'right') - 1, clipped — block-wide count (3 barriers)
        int i0 = __syncthreads_count(myts <= tv0);
        int i1 = __syncthreads_count(myts <= tv1);
        int i2 = __syncthreads_count(myts <= tv2);
        i0 = min(max(i0 - 1, 0), TT - 2);
        i1 = min(max(i1 - 1, 0), TT - 2);
        i2 = min(max(i2 - 1, 0), TT - 2);

        const float* yin = ybuf;
        #pragma unroll 1
        for (int q = 0; q < 3; ++q) {
            // ---- hidden layer 1: h1 = softplus(w0 @ yin + fb0), 8 lanes/row ----
            {
                const float* wr = w0 + row8 * WSTR + oct * 16;
                const float* xr = yin + oct * 16;
                float acc = 0.f;
                #pragma unroll
                for (int k = 0; k < 16; k += 4) {
                    float4 w4 = *(const float4*)(wr + k);
                    float4 x4 = *(const float4*)(xr + k);
                    acc += w4.x * x4.x + w4.y * x4.y + w4.z * x4.z + w4.w * x4.w;
                }
                acc += __shfl_xor(acc, 1); acc += __shfl_xor(acc, 2); acc += __shfl_xor(acc, 4);
                if (oct == 0) h1b[row8] = softplus_f(acc + fb0[row8]);
            }
            // dvec for all 3 RK stages (computed once, overlapped with stage-0 h1/h2)
            if (q == 0 && tid < 96) {
                int qq = tid >> 5, d = tid & 31;
                int idx = (qq == 0) ? i0 : (qq == 1) ? i1 : i2;
                float tv = (qq == 0) ? tv0 : (qq == 1) ? tv1 : tv2;
                float frac = tv - tss[idx];
                size_t o = (size_t)idx * DD + d;
                dvec[qq * DD + d] = cbb[o] + frac * (2.f * ccb[o] + frac * 3.f * cdb[o]);
            }
            __syncthreads();
            // ---- hidden layer 2 ----
            {
                const float* wr = w1 + row8 * WSTR + oct * 16;
                const float* xr = h1b + oct * 16;
                float acc = 0.f;
                #pragma unroll
                for (int k = 0; k < 16; k += 4) {
                    float4 w4 = *(const float4*)(wr + k);
                    float4 x4 = *(const float4*)(xr + k);
                    acc += w4.x * x4.x + w4.y * x4.y + w4.z * x4.z + w4.w * x4.w;
                }
                acc += __shfl_xor(acc, 1); acc += __shfl_xor(acc, 2); acc += __shfl_xor(acc, 4);
                if (oct == 0) h2b[row8] = softplus_f(acc + fb1[row8]);
            }
            __syncthreads();

            // ---- big matvec via MFMA: rowbuf[r] = fW2[r,:] . h2 ----
            // B fragment: broadcast h2 across all 16 cols (k = (lane>>4)*8+j)
            short8 bfr[4];
            {
                const int kb = (lane >> 4) * 8;
                #pragma unroll
                for (int K = 0; K < 4; ++K) {
                    #pragma unroll
                    for (int j = 0; j < 8; ++j) bfr[K][j] = bf16rne(h2b[K * 32 + kb + j]);
                }
            }
            #pragma unroll 1
            for (int i = 0; i < 8; ++i) {
                const int h = wv * 8 + i;
                const short* base = w2p + ((size_t)(h * 8) << 9) + lane * 8;
                short8 a0 = *(const short8*)(base);
                short8 a1 = *(const short8*)(base + 512);
                short8 a2 = *(const short8*)(base + 1024);
                short8 a3 = *(const short8*)(base + 1536);
                short8 a4 = *(const short8*)(base + 2048);
                short8 a5 = *(const short8*)(base + 2560);
                short8 a6 = *(const short8*)(base + 3072);
                short8 a7 = *(const short8*)(base + 3584);
                f32x4 acc0 = {0.f, 0.f, 0.f, 0.f};
                f32x4 acc1 = {0.f, 0.f, 0.f, 0.f};
                acc0 = __builtin_amdgcn_mfma_f32_16x16x32_bf16(a0, bfr[0], acc0, 0, 0, 0);
                acc0 = __builtin_amdgcn_mfma_f32_16x16x32_bf16(a1, bfr[1], acc0, 0, 0, 0);
                acc0 = __builtin_amdgcn_mfma_f32_16x16x32_bf16(a2, bfr[2], acc0, 0, 0, 0);
                acc0 = __builtin_amdgcn_mfma_f32_16x16x32_bf16(a3, bfr[3], acc0, 0, 0, 0);
                acc1 = __builtin_amdgcn_mfma_f32_16x16x32_bf16(a4, bfr[0], acc1, 0, 0, 0);
                acc1 = __builtin_amdgcn_mfma_f32_16x16x32_bf16(a5, bfr[1], acc1, 0, 0, 0);
                acc1 = __builtin_amdgcn_mfma_f32_16x16x32_bf16(a6, bfr[2], acc1, 0, 0, 0);
                acc1 = __builtin_amdgcn_mfma_f32_16x16x32_bf16(a7, bfr[3], acc1, 0, 0, 0);
                if ((lane & 15) == 0) {
                    // C/D layout: col = lane&15 (=0 here), row = (lane>>4)*4 + reg
                    const int r0 = h * 32 + (lane >> 4) * 4;
                    float4 v0, v1;
                    v0.x = acc0[0]; v0.y = acc0[1]; v0.z = acc0[2]; v0.w = acc0[3];
                    v1.x = acc1[0]; v1.y = acc1[1]; v1.z = acc1[2]; v1.w = acc1[3];
                    *(float4*)(rowbuf + r0)      = v0;   // tile t=0: d = 0..15
                    *(float4*)(rowbuf + r0 + 16) = v1;   // tile t=1: d = 16..31
                }
            }
            __syncthreads();

            // ---- tanh + contract over D + RK update (rows r = tid*4..+3) ----
            {
                float4 rv = *(const float4*)(rowbuf + tid * 4);
                float4 bv = *(const float4*)(fb2 + tid * 4);
                float4 dv = *(const float4*)(dvec + q * DD + oct * 4);
                float p = fast_tanh(rv.x + bv.x) * dv.x
                        + fast_tanh(rv.y + bv.y) * dv.y
                        + fast_tanh(rv.z + bv.z) * dv.z
                        + fast_tanh(rv.w + bv.w) * dv.w;
                p += __shfl_xor(p, 1); p += __shfl_xor(p, 2); p += __shfl_xor(p, 4);
                if (oct == 0) {
                    const int h = row8;
                    float kv = p * dt;   // f = (M @ deriv) * dt
                    if (q == 0)      { k1b[h] = kv; ytmp[h] = ybuf[h] + 0.5f  * kv; }
                    else if (q == 1) { k2b[h] = kv; ytmp[h] = ybuf[h] + 0.75f * kv; }
                    else {
                        ybuf[h] = ybuf[h] + dt * ((2.f/9.f) * k1b[h] + (1.f/3.f) * k2b[h] + (4.f/9.f) * kv);
                    }
                }
            }
            __syncthreads();
            yin = ytmp;
        }

        // ---- readout: sigmoid(y . lW + lb) — wave 0; next barrier orders vs h1 ----
        if (wv == 0) {
            float p = ybuf[lane] * lw0 + ybuf[lane + 64] * lw1;
            p += __shfl_xor(p, 1);  p += __shfl_xor(p, 2);  p += __shfl_xor(p, 4);
            p += __shfl_xor(p, 8);  p += __shfl_xor(p, 16); p += __shfl_xor(p, 32);
            if (lane == 0) out[(size_t)b * TT + s] = 1.f / (1.f + __expf(-(p + lbv)));
        }
        t0 += dt;
    }
}

extern "C" void kernel_launch(void* const* d_in, const int* in_sizes, int n_in,
                              void* d_out, int out_size, void* d_ws, size_t ws_size,
                              hipStream_t stream) {
    const float* ts  = (const float*)d_in[0];
    const float* cdp = (const float*)d_in[1];
    const float* ccp = (const float*)d_in[2];
    const float* cbp = (const float*)d_in[3];
    const float* cap = (const float*)d_in[4];
    const float* iW0 = (const float*)d_in[5];
    const float* ib0 = (const float*)d_in[6];
    const float* iW1 = (const float*)d_in[7];
    const float* ib1 = (const float*)d_in[8];
    const float* iW2 = (const float*)d_in[9];
    const float* ib2 = (const float*)d_in[10];
    const float* fW0 = (const float*)d_in[11];
    const float* fb0 = (const float*)d_in[12];
    const float* fW1 = (const float*)d_in[13];
    const float* fb1 = (const float*)d_in[14];
    const float* fW2 = (const float*)d_in[15];
    const float* fb2 = (const float*)d_in[16];
    const float* lW  = (const float*)d_in[17];
    const float* lb  = (const float*)d_in[18];
    float* out = (float*)d_out;

    const int n_w2 = HD * WW;  // 524288
    short* w2p = (short*)d_ws;

    const size_t smem_bytes = SMEM_FLOATS * sizeof(float);

    hipLaunchKernelGGL(cvt_w2_perm, dim3((n_w2 + 255) / 256), dim3(256), 0, stream,
                       fW2, w2p, n_w2);
    hipFuncSetAttribute((const void*)cde_kernel,
                        hipFuncAttributeMaxDynamicSharedMemorySize, (int)smem_bytes);
    hipLaunchKernelGGL(cde_kernel, dim3(BB), dim3(NTHR), smem_bytes, stream,
                       ts, cdp, ccp, cbp, cap, iW0, ib0, iW1, ib1, iW2, ib2,
                       fW0, fb0, fW1, fb1, fb2, lW, lb, w2p, out);
}